// Round 4
// baseline (424.316 us; speedup 1.0000x reference)
//
#include <hip/hip_runtime.h>

// LocallyLowRank: N=4, A=16, H=W=384, 8x8 blocks stride 4 -> NB=95.
// Per block: m = 64x16 (P=64 pixels x A=16 ch), SVD soft-threshold (tau=2):
//   m' = m * Phi, Phi = V diag(max(1-2/sigma,0)) V^T,  G = m^T m = V diag(s^2) V^T.
// Eigensolve: one-sided (Hestenes) Jacobi on G columns (W = G V, w_k = lam_k v_k).
//
// R4 = R2/R3 design with the __ballot convergence skip removed (de-risk after
// two content-free bench-driver failures). 256-thread blocks = 4 independent
// waves, each wave owns 4 matrices and PRIVATE LDS buffers -> no __syncthreads
// (intra-wave DS ops are in-order; wave_barrier pins compiler ordering).
// Gram in two 32-pixel halves so Mt is 16x36 fp32 -> 29952 B/block ->
// 5 blocks/CU = 20 waves/CU (64-thread blocks cap at 16 WG/CU, hence 4-wave
// blocks). NSWEEP 4.

#define N_      4
#define A_      16
#define H_      384
#define W_      384
#define PLANE_  (H_*W_)       // 147456
#define NB_     95
#define NBB_    (NB_*NB_)     // 9025
#define NMAT_   (N_*NBB_)     // 36100
#define NWAVE_  ((NMAT_ + 3) / 4)   // 9025 waves, 4 matrices each
#define NSWEEP_ 4

__global__ __launch_bounds__(256, 5)
void llr_main(const float* __restrict__ x, float* __restrict__ out) {
    // Per-wave private buffers (indexed by warp id):
    // Mt: half-staged matrix, transposed: Mt[ch][pixel], row stride 36 floats
    //     (float4-aligned; 36 mod 32 = 4 -> rows jj / jj+8 alias = 2-way, free).
    // Gl: 16x16 matrix as columns, col stride 20 floats (slot 16 = rho).
    //     Reused: G -> W(+rho) -> Phi.
    __shared__ __align__(16) float Mt[4][16][36];
    __shared__ __align__(16) float Gl[4][4][324];

    const int warp = threadIdx.x >> 6;
    const int lane = threadIdx.x & 63;
    const int wid  = blockIdx.x * 4 + warp;    // global wave id
    if (wid >= NWAVE_) return;                 // tail waves: no barriers -> safe

    const int g    = lane >> 4;     // matrix slot within wave
    const int j    = lane & 15;     // column index within matrix

    const int jj  = lane & 15;      // Gram: G row handled by this lane
    const int kq4 = (lane >> 4) * 4;// Gram: 4-column group handled

    // staging role: 32 lanes = 32 pixels of the half, 2 channel-groups of 8
    const int pl  = lane & 31;            // pixel within half
    const int chb = (lane >> 5) * 8;      // channel base (0 or 8)

    // ---------------- Phase 1: stage + Gram, 4 matrices, 2 halves each ------
    for (int s = 0; s < 4; ++s) {
        const int id  = wid * 4 + s;
        const int n   = id / NBB_;
        const int rem = id % NBB_;
        const int bi  = rem / NB_;
        const int bj  = rem % NB_;
        const int pbase = n * (A_ * PLANE_) + bi*4*W_ + bj*4;

        float a0 = 0.f, a1 = 0.f, a2 = 0.f, a3 = 0.f;
        for (int h = 0; h < 2; ++h) {
            const int p  = h*32 + pl;            // pixel 0..63
            const int base = pbase + (p >> 3) * W_ + (p & 7);
            __builtin_amdgcn_wave_barrier();     // protect Mt from prev readers
            #pragma unroll
            for (int a = 0; a < 8; ++a)
                Mt[warp][chb + a][pl] = x[base + (chb + a) * PLANE_];
            __builtin_amdgcn_wave_barrier();

            // G[jj][kq4+i] += sum_p Mt[jj][p]*Mt[kq4+i][p]
            #pragma unroll
            for (int p4 = 0; p4 < 32; p4 += 4) {
                const float4 av = *(const float4*)&Mt[warp][jj][p4];
                const float4 b0 = *(const float4*)&Mt[warp][kq4 + 0][p4];
                const float4 b1 = *(const float4*)&Mt[warp][kq4 + 1][p4];
                const float4 b2 = *(const float4*)&Mt[warp][kq4 + 2][p4];
                const float4 b3 = *(const float4*)&Mt[warp][kq4 + 3][p4];
                a0 += av.x*b0.x + av.y*b0.y + av.z*b0.z + av.w*b0.w;
                a1 += av.x*b1.x + av.y*b1.y + av.z*b1.z + av.w*b1.w;
                a2 += av.x*b2.x + av.y*b2.y + av.z*b2.z + av.w*b2.w;
                a3 += av.x*b3.x + av.y*b3.y + av.z*b3.z + av.w*b3.w;
            }
            __builtin_amdgcn_wave_barrier();
        }
        // G symmetric: row jj stored as column jj.
        *(float4*)&Gl[warp][s][jj*20 + kq4] = make_float4(a0, a1, a2, a3);
    }
    __builtin_amdgcn_wave_barrier();

    // ---------------- Phase 2: read my column into registers ----------------
    float w[16];
    {
        const float4 t0 = *(const float4*)&Gl[warp][g][j*20 + 0];
        const float4 t1 = *(const float4*)&Gl[warp][g][j*20 + 4];
        const float4 t2 = *(const float4*)&Gl[warp][g][j*20 + 8];
        const float4 t3 = *(const float4*)&Gl[warp][g][j*20 + 12];
        w[0]=t0.x; w[1]=t0.y; w[2]=t0.z; w[3]=t0.w;
        w[4]=t1.x; w[5]=t1.y; w[6]=t1.z; w[7]=t1.w;
        w[8]=t2.x; w[9]=t2.y; w[10]=t2.z; w[11]=t2.w;
        w[12]=t3.x; w[13]=t3.y; w[14]=t3.z; w[15]=t3.w;
    }
    float nrm = 0.f;   // ||w_j||^2, maintained analytically per rotation
    #pragma unroll
    for (int i = 0; i < 16; ++i) nrm += w[i] * w[i];

    // ---------------- Phase 3: one-sided Jacobi (register-resident) ---------
    for (int sweep = 0; sweep < NSWEEP_; ++sweep) {
        #pragma unroll
        for (int m = 1; m < 16; ++m) {          // xor tournament: all 120 pairs
            float pw[16];
            #pragma unroll
            for (int i = 0; i < 16; ++i) pw[i] = __shfl_xor(w[i], m, 16);
            const float pn = __shfl_xor(nrm, m, 16);

            float gam = 0.f;                    // w_p . w_q (identical in pair)
            #pragma unroll
            for (int i = 0; i < 16; ++i) gam += w[i] * pw[i];

            const bool  low = ((j ^ m) > j);    // canonical order -> identical c,s
            const float na  = low ? nrm : pn;
            const float nb  = low ? pn  : nrm;

            const float thr = 1e-12f * (na + nb);
            const bool  rot = fabsf(gam) > thr;
            const float gs  = rot ? gam : 1.f;
            const float zeta = (nb - na) / (2.f * gs);
            float t = copysignf(1.f, zeta) / (fabsf(zeta) + sqrtf(1.f + zeta*zeta));
            float c = rsqrtf(1.f + t*t);
            float sv = c * t;
            if (!rot) { c = 1.f; sv = 0.f; }

            const float ss = low ? -sv : sv;
            #pragma unroll
            for (int i = 0; i < 16; ++i) w[i] = c*w[i] + ss*pw[i];

            const float cc = c*c, s2 = sv*sv, x2 = 2.f*c*sv*gam;
            nrm = low ? (cc*na + s2*nb - x2) : (s2*na + cc*nb + x2);
        }
    }
    // exact norm (removes analytic drift)
    nrm = 0.f;
    #pragma unroll
    for (int i = 0; i < 16; ++i) nrm += w[i] * w[i];

    // rho = max(1 - 2/sigma, 0)/lam^2 ; lam = sqrt(nrm), sigma = sqrt(lam).
    float rho = 0.f;
    if (nrm > 16.f) {
        const float lam = sqrtf(nrm);
        const float sig = sqrtf(lam);
        rho = (1.f - 2.f / sig) / nrm;
    }

    __builtin_amdgcn_wave_barrier();
    // write W columns + rho back into Gl
    *(float4*)&Gl[warp][g][j*20 + 0]  = make_float4(w[0], w[1], w[2], w[3]);
    *(float4*)&Gl[warp][g][j*20 + 4]  = make_float4(w[4], w[5], w[6], w[7]);
    *(float4*)&Gl[warp][g][j*20 + 8]  = make_float4(w[8], w[9], w[10], w[11]);
    *(float4*)&Gl[warp][g][j*20 + 12] = make_float4(w[12], w[13], w[14], w[15]);
    Gl[warp][g][j*20 + 16] = rho;
    __builtin_amdgcn_wave_barrier();

    // ---------------- Phase 4: Phi column j = sum_k (rho_k w_k[j]) w_k ------
    float phi[16];
    #pragma unroll
    for (int i = 0; i < 16; ++i) phi[i] = 0.f;
    #pragma unroll
    for (int k = 0; k < 16; ++k) {
        const float coef = Gl[warp][g][k*20 + 16] * Gl[warp][g][k*20 + j];
        const float4 c0 = *(const float4*)&Gl[warp][g][k*20 + 0];
        const float4 c1 = *(const float4*)&Gl[warp][g][k*20 + 4];
        const float4 c2 = *(const float4*)&Gl[warp][g][k*20 + 8];
        const float4 c3 = *(const float4*)&Gl[warp][g][k*20 + 12];
        phi[0]+=coef*c0.x; phi[1]+=coef*c0.y; phi[2]+=coef*c0.z; phi[3]+=coef*c0.w;
        phi[4]+=coef*c1.x; phi[5]+=coef*c1.y; phi[6]+=coef*c1.z; phi[7]+=coef*c1.w;
        phi[8]+=coef*c2.x; phi[9]+=coef*c2.y; phi[10]+=coef*c2.z; phi[11]+=coef*c2.w;
        phi[12]+=coef*c3.x; phi[13]+=coef*c3.y; phi[14]+=coef*c3.z; phi[15]+=coef*c3.w;
    }
    __builtin_amdgcn_wave_barrier();          // all reads of W done
    *(float4*)&Gl[warp][g][j*20 + 0]  = make_float4(phi[0], phi[1], phi[2], phi[3]);
    *(float4*)&Gl[warp][g][j*20 + 4]  = make_float4(phi[4], phi[5], phi[6], phi[7]);
    *(float4*)&Gl[warp][g][j*20 + 8]  = make_float4(phi[8], phi[9], phi[10], phi[11]);
    *(float4*)&Gl[warp][g][j*20 + 12] = make_float4(phi[12], phi[13], phi[14], phi[15]);
    __builtin_amdgcn_wave_barrier();

    // ---------------- Phase 5: out += M * Phi (lane = pixel) ----------------
    // Phi symmetric: o[a] += M[p][k]*Phi[k][a] via column-k broadcast reads.
    const int pr = lane >> 3;
    const int pc = lane & 7;
    for (int s = 0; s < 4; ++s) {
        const int id  = wid * 4 + s;
        const int n   = id / NBB_;
        const int rem = id % NBB_;
        const int bi  = rem / NB_;
        const int bj  = rem % NB_;
        const int base = n * (A_ * PLANE_) + (bi*4 + pr) * W_ + (bj*4 + pc);

        float mr[16];
        #pragma unroll
        for (int a = 0; a < 16; ++a) mr[a] = x[base + a * PLANE_];  // L2-hot reload

        float o[16];
        #pragma unroll
        for (int a = 0; a < 16; ++a) o[a] = 0.f;
        #pragma unroll
        for (int k = 0; k < 16; ++k) {
            const float mk = mr[k];
            const float4 f0 = *(const float4*)&Gl[warp][s][k*20 + 0];   // broadcast
            const float4 f1 = *(const float4*)&Gl[warp][s][k*20 + 4];
            const float4 f2 = *(const float4*)&Gl[warp][s][k*20 + 8];
            const float4 f3 = *(const float4*)&Gl[warp][s][k*20 + 12];
            o[0]+=mk*f0.x;  o[1]+=mk*f0.y;  o[2]+=mk*f0.z;  o[3]+=mk*f0.w;
            o[4]+=mk*f1.x;  o[5]+=mk*f1.y;  o[6]+=mk*f1.z;  o[7]+=mk*f1.w;
            o[8]+=mk*f2.x;  o[9]+=mk*f2.y;  o[10]+=mk*f2.z; o[11]+=mk*f2.w;
            o[12]+=mk*f3.x; o[13]+=mk*f3.y; o[14]+=mk*f3.z; o[15]+=mk*f3.w;
        }
        // native fp32 fadd atomics; contention only ~4 blocks/address.
        #pragma unroll
        for (int a = 0; a < 16; ++a)
            unsafeAtomicAdd(&out[base + a * PLANE_], o[a]);
    }
}

// out /= block_weights (broadcast over the N*A=64 planes)
__global__ __launch_bounds__(256)
void llr_div(float* __restrict__ out, const float* __restrict__ bw) {
    const int i = (blockIdx.x * 256 + threadIdx.x) * 4;   // grid sized exactly
    float4 o = *(float4*)&out[i];
    const float4 b = *(const float4*)&bw[i % PLANE_];
    o.x /= b.x; o.y /= b.y; o.z /= b.z; o.w /= b.w;
    *(float4*)&out[i] = o;
}

extern "C" void kernel_launch(void* const* d_in, const int* in_sizes, int n_in,
                              void* d_out, int out_size, void* d_ws, size_t ws_size,
                              hipStream_t stream) {
    (void)in_sizes; (void)n_in; (void)d_ws; (void)ws_size;
    const float* x  = (const float*)d_in[0];
    const float* bw = (const float*)d_in[1];
    float* out = (float*)d_out;

    // harness poisons d_out with 0xAA before every launch -> zero it ourselves
    hipMemsetAsync(out, 0, (size_t)out_size * sizeof(float), stream);

    const int nblocks = (NWAVE_ + 3) / 4;   // 2257 blocks x 4 waves
    hipLaunchKernelGGL(llr_main, dim3(nblocks), dim3(256), 0, stream, x, out);
    hipLaunchKernelGGL(llr_div,  dim3((N_*A_*PLANE_) / (256*4)), dim3(256), 0, stream, out, bw);
}

// Round 5
// 265.381 us; speedup vs baseline: 1.5989x; 1.5989x over previous
//
#include <hip/hip_runtime.h>

// LocallyLowRank: N=4, A=16, H=W=384, 8x8 blocks stride 4 -> NB=95.
// Per block b: m_b = 64x16 (P pixels x A ch), SVD soft-threshold (tau=2):
//   m' = m * Phi_b, Phi_b = V max(1-2/sigma,0) V^T, G = m^T m.
// KEY IDENTITY (R5): row p of m_b is x[p,:], so the overlap-add output is
//   out[p,:] = sum_{b covering p} x[p,:]*Phi_b = x[p,:] * S_p,  S_p = sum Phi_b
// -> K1 computes Phi only (no scatter, no atomics); K2 sums <=4 Phi per 4x4
// pixel cell (constant covering set per cell) and writes out exactly once.
//
// Eigensolve: one-sided (Hestenes) Jacobi on G columns (W = G V, w_k = lam v_k),
// 16 lanes per matrix, 4 matrices per wave, xor-tournament masks 1..15, 4 sweeps.
// Masks 1,2,3 (quad_perm), 7 (row_half_mirror), 15 (row_mirror) run on the VALU
// via DPP -> ~1/3 of swizzle traffic off the DS pipe.

#define N_      4
#define A_      16
#define H_      384
#define W_      384
#define PLANE_  (H_*W_)       // 147456
#define NB_     95
#define NBB_    (NB_*NB_)     // 9025
#define NMAT_   (N_*NBB_)     // 36100
#define NWAVE_  ((NMAT_ + 3) / 4)   // 9025
#define NSWEEP_ 4
#define NC_     96            // 4px cells per dim
#define PHI_BYTES_ ((size_t)NMAT_ * 256 * 4)   // 36.97 MB

// ---- 16-lane xor exchange: DPP for masks 1,2,3,7,15; ds_swizzle otherwise ---
template<int M>
__device__ __forceinline__ float lane_xor16(float v) {
    if constexpr (M == 1 || M == 2 || M == 3) {
        constexpr int ctrl = (0^M) | ((1^M)<<2) | ((2^M)<<4) | ((3^M)<<6);
        union { float f; int i; } u; u.f = v;
        u.i = __builtin_amdgcn_mov_dpp(u.i, ctrl, 0xF, 0xF, true);
        return u.f;
    } else if constexpr (M == 7) {          // row_half_mirror = lane^7
        union { float f; int i; } u; u.f = v;
        u.i = __builtin_amdgcn_mov_dpp(u.i, 0x141, 0xF, 0xF, true);
        return u.f;
    } else if constexpr (M == 15) {         // row_mirror = lane^15
        union { float f; int i; } u; u.f = v;
        u.i = __builtin_amdgcn_mov_dpp(u.i, 0x140, 0xF, 0xF, true);
        return u.f;
    } else {
        return __shfl_xor(v, M, 16);        // compile-time M -> ds_swizzle
    }
}

template<int M>
__device__ __forceinline__ void jacobi_round(float w[16], float& nrm, const int j) {
    float pw[16];
    #pragma unroll
    for (int i = 0; i < 16; ++i) pw[i] = lane_xor16<M>(w[i]);
    const float pn = lane_xor16<M>(nrm);

    // balanced-tree dot: depth ~5 instead of 16
    float t8[8];
    #pragma unroll
    for (int i = 0; i < 8; ++i) t8[i] = w[i]*pw[i] + w[i+8]*pw[i+8];
    const float t40 = t8[0]+t8[4], t41 = t8[1]+t8[5],
                t42 = t8[2]+t8[6], t43 = t8[3]+t8[7];
    const float gam = (t40+t42) + (t41+t43);

    const bool  low = ((j ^ M) > j);        // canonical order -> identical c,s in pair
    const float na  = low ? nrm : pn;
    const float nb  = low ? pn  : nrm;

    const float thr = 1e-12f * (na + nb);
    const bool  rot = fabsf(gam) > thr;
    const float gs  = rot ? gam : 1.f;
    const float zeta = (nb - na) / (2.f * gs);
    float t = copysignf(1.f, zeta) / (fabsf(zeta) + sqrtf(1.f + zeta*zeta));
    float c = rsqrtf(1.f + t*t);
    float sv = c * t;
    if (!rot) { c = 1.f; sv = 0.f; }

    const float ss = low ? -sv : sv;
    #pragma unroll
    for (int i = 0; i < 16; ++i) w[i] = c*w[i] + ss*pw[i];

    const float cc = c*c, s2 = sv*sv, x2 = 2.f*c*sv*gam;
    nrm = low ? (cc*na + s2*nb - x2) : (s2*na + cc*nb + x2);
}

// =================== K1: Gram + Jacobi -> Phi (global) ======================
__global__ __launch_bounds__(256, 6)
void llr_phi(const float* __restrict__ x, float* __restrict__ phiG) {
    // Per-wave private LDS (no __syncthreads anywhere):
    // Mt: quarter-staged matrix, Mt[ch][pixel], row stride 20 (16B-aligned;
    //     2-way bank alias only -> free).
    // Gl: 16x16 as columns, col stride 20 (slot16 = rho), group skew 324.
    __shared__ __align__(16) float Mt[4][16][20];
    __shared__ __align__(16) float Gl[4][4][324];

    const int warp = threadIdx.x >> 6;
    const int lane = threadIdx.x & 63;
    const int wid  = blockIdx.x * 4 + warp;
    if (wid >= NWAVE_) return;              // no barriers -> safe early exit

    const int g   = lane >> 4;              // matrix slot / channel-group / col-group
    const int j   = lane & 15;              // column (and Gram row, and pixel-in-quarter)
    const int kq4 = g * 4;

    // ---------------- Phase 1: stage + Gram, 4 matrices, 4 quarters each ----
    for (int s = 0; s < 4; ++s) {
        const int id  = wid * 4 + s;
        const int n   = id / NBB_;
        const int rem = id % NBB_;
        const int bi  = rem / NB_;
        const int bj  = rem % NB_;
        const int pbase = n * (A_ * PLANE_) + bi*4*W_ + bj*4;

        float a0 = 0.f, a1 = 0.f, a2 = 0.f, a3 = 0.f;
        for (int q = 0; q < 4; ++q) {
            const int p    = q*16 + j;               // pixel 0..63
            const int base = pbase + (p >> 3) * W_ + (p & 7);
            __builtin_amdgcn_wave_barrier();          // Mt reuse ordering
            #pragma unroll
            for (int t = 0; t < 4; ++t)               // lane stages 4 channels
                Mt[warp][kq4 + t][j] = x[base + (kq4 + t) * PLANE_];
            __builtin_amdgcn_wave_barrier();

            #pragma unroll
            for (int p4 = 0; p4 < 16; p4 += 4) {
                const float4 av = *(const float4*)&Mt[warp][j][p4];
                const float4 b0 = *(const float4*)&Mt[warp][kq4 + 0][p4];
                const float4 b1 = *(const float4*)&Mt[warp][kq4 + 1][p4];
                const float4 b2 = *(const float4*)&Mt[warp][kq4 + 2][p4];
                const float4 b3 = *(const float4*)&Mt[warp][kq4 + 3][p4];
                a0 += av.x*b0.x + av.y*b0.y + av.z*b0.z + av.w*b0.w;
                a1 += av.x*b1.x + av.y*b1.y + av.z*b1.z + av.w*b1.w;
                a2 += av.x*b2.x + av.y*b2.y + av.z*b2.z + av.w*b2.w;
                a3 += av.x*b3.x + av.y*b3.y + av.z*b3.z + av.w*b3.w;
            }
            __builtin_amdgcn_wave_barrier();
        }
        *(float4*)&Gl[warp][s][j*20 + kq4] = make_float4(a0, a1, a2, a3);
    }
    __builtin_amdgcn_wave_barrier();

    // ---------------- Phase 2: my column into registers ---------------------
    float w[16];
    {
        const float4 t0 = *(const float4*)&Gl[warp][g][j*20 + 0];
        const float4 t1 = *(const float4*)&Gl[warp][g][j*20 + 4];
        const float4 t2 = *(const float4*)&Gl[warp][g][j*20 + 8];
        const float4 t3 = *(const float4*)&Gl[warp][g][j*20 + 12];
        w[0]=t0.x; w[1]=t0.y; w[2]=t0.z; w[3]=t0.w;
        w[4]=t1.x; w[5]=t1.y; w[6]=t1.z; w[7]=t1.w;
        w[8]=t2.x; w[9]=t2.y; w[10]=t2.z; w[11]=t2.w;
        w[12]=t3.x; w[13]=t3.y; w[14]=t3.z; w[15]=t3.w;
    }
    float nrm = 0.f;
    #pragma unroll
    for (int i = 0; i < 16; ++i) nrm += w[i] * w[i];

    // ---------------- Phase 3: one-sided Jacobi -----------------------------
    for (int sweep = 0; sweep < NSWEEP_; ++sweep) {
        jacobi_round<1>(w, nrm, j);  jacobi_round<2>(w, nrm, j);
        jacobi_round<3>(w, nrm, j);  jacobi_round<4>(w, nrm, j);
        jacobi_round<5>(w, nrm, j);  jacobi_round<6>(w, nrm, j);
        jacobi_round<7>(w, nrm, j);  jacobi_round<8>(w, nrm, j);
        jacobi_round<9>(w, nrm, j);  jacobi_round<10>(w, nrm, j);
        jacobi_round<11>(w, nrm, j); jacobi_round<12>(w, nrm, j);
        jacobi_round<13>(w, nrm, j); jacobi_round<14>(w, nrm, j);
        jacobi_round<15>(w, nrm, j);
    }
    nrm = 0.f;                               // exact norm (drift removal)
    #pragma unroll
    for (int i = 0; i < 16; ++i) nrm += w[i] * w[i];

    float rho = 0.f;                         // max(1-2/sigma,0)/lam^2
    if (nrm > 16.f) {
        const float lam = sqrtf(nrm);
        const float sig = sqrtf(lam);
        rho = (1.f - 2.f / sig) / nrm;
    }

    __builtin_amdgcn_wave_barrier();
    *(float4*)&Gl[warp][g][j*20 + 0]  = make_float4(w[0], w[1], w[2], w[3]);
    *(float4*)&Gl[warp][g][j*20 + 4]  = make_float4(w[4], w[5], w[6], w[7]);
    *(float4*)&Gl[warp][g][j*20 + 8]  = make_float4(w[8], w[9], w[10], w[11]);
    *(float4*)&Gl[warp][g][j*20 + 12] = make_float4(w[12], w[13], w[14], w[15]);
    Gl[warp][g][j*20 + 16] = rho;
    __builtin_amdgcn_wave_barrier();

    // ---------------- Phase 4: Phi col j = sum_k rho_k w_k[j] w_k -> global -
    float phi[16];
    #pragma unroll
    for (int i = 0; i < 16; ++i) phi[i] = 0.f;
    #pragma unroll
    for (int k = 0; k < 16; ++k) {
        const float coef = Gl[warp][g][k*20 + 16] * Gl[warp][g][k*20 + j];
        const float4 c0 = *(const float4*)&Gl[warp][g][k*20 + 0];
        const float4 c1 = *(const float4*)&Gl[warp][g][k*20 + 4];
        const float4 c2 = *(const float4*)&Gl[warp][g][k*20 + 8];
        const float4 c3 = *(const float4*)&Gl[warp][g][k*20 + 12];
        phi[0]+=coef*c0.x; phi[1]+=coef*c0.y; phi[2]+=coef*c0.z; phi[3]+=coef*c0.w;
        phi[4]+=coef*c1.x; phi[5]+=coef*c1.y; phi[6]+=coef*c1.z; phi[7]+=coef*c1.w;
        phi[8]+=coef*c2.x; phi[9]+=coef*c2.y; phi[10]+=coef*c2.z; phi[11]+=coef*c2.w;
        phi[12]+=coef*c3.x; phi[13]+=coef*c3.y; phi[14]+=coef*c3.z; phi[15]+=coef*c3.w;
    }
    // Phi symmetric -> column j IS row j: store 64B contiguous per lane.
    {
        float* pb = phiG + (size_t)(wid*4 + g) * 256 + j * 16;
        *(float4*)&pb[0]  = make_float4(phi[0],  phi[1],  phi[2],  phi[3]);
        *(float4*)&pb[4]  = make_float4(phi[4],  phi[5],  phi[6],  phi[7]);
        *(float4*)&pb[8]  = make_float4(phi[8],  phi[9],  phi[10], phi[11]);
        *(float4*)&pb[12] = make_float4(phi[12], phi[13], phi[14], phi[15]);
    }
}

// =================== K2: out[p,:] = x[p,:] * mean(covering Phi) =============
__global__ __launch_bounds__(256, 8)
void llr_out(const float* __restrict__ x, const float* __restrict__ phiG,
             float* __restrict__ out) {
    __shared__ __align__(16) float Sl[4][256];
    const int warp = threadIdx.x >> 6;
    const int lane = threadIdx.x & 63;
    const int cid  = blockIdx.x * 4 + warp;        // 4*96*96 = 36864 cells exact
    const int n    = cid / (NC_*NC_);
    const int rem  = cid % (NC_*NC_);
    const int ci   = rem / NC_;
    const int cj   = rem % NC_;

    // S = sum of covering Phi (cooperative: lane holds flat [4*lane..4*lane+3])
    float4 s = make_float4(0.f, 0.f, 0.f, 0.f);
    #pragma unroll
    for (int dbi = -1; dbi <= 0; ++dbi) {
        const int bi = ci + dbi;
        if (bi < 0 || bi > NB_-1) continue;
        #pragma unroll
        for (int dbj = -1; dbj <= 0; ++dbj) {
            const int bj = cj + dbj;
            if (bj < 0 || bj > NB_-1) continue;
            const float4 p = *(const float4*)&phiG[((size_t)(n*NBB_ + bi*NB_ + bj))*256 + lane*4];
            s.x += p.x; s.y += p.y; s.z += p.z; s.w += p.w;
        }
    }
    __builtin_amdgcn_wave_barrier();
    *(float4*)&Sl[warp][lane*4] = s;
    __builtin_amdgcn_wave_barrier();

    const float invw = 1.f / (float)(((ci >= 1) + (ci <= NB_-1)) *
                                     ((cj >= 1) + (cj <= NB_-1)));   // 1,2,4 exact

    // lane = (chgroup, pixel): px 0..15 in 4x4 cell, 4 output channels per lane
    const int px = lane & 15, cg = lane >> 4;
    const int r   = ci*4 + (px >> 2);
    const int col = cj*4 + (px & 3);
    const size_t sb = (size_t)n * (A_*PLANE_) + (size_t)r * W_ + col;

    float4 acc = make_float4(0.f, 0.f, 0.f, 0.f);
    #pragma unroll
    for (int c = 0; c < 16; ++c) {
        const float  xv   = x[sb + (size_t)c * PLANE_];
        const float4 Srow = *(const float4*)&Sl[warp][c*16 + cg*4]; // broadcast
        acc.x += xv*Srow.x; acc.y += xv*Srow.y; acc.z += xv*Srow.z; acc.w += xv*Srow.w;
    }
    acc.x *= invw; acc.y *= invw; acc.z *= invw; acc.w *= invw;

    out[sb + (size_t)(cg*4 + 0) * PLANE_] = acc.x;
    out[sb + (size_t)(cg*4 + 1) * PLANE_] = acc.y;
    out[sb + (size_t)(cg*4 + 2) * PLANE_] = acc.z;
    out[sb + (size_t)(cg*4 + 3) * PLANE_] = acc.w;
}

// =================== Fallback (ws too small): R4 fused path =================
__global__ __launch_bounds__(256, 5)
void llr_fused(const float* __restrict__ x, float* __restrict__ out) {
    __shared__ __align__(16) float Mt[4][16][36];
    __shared__ __align__(16) float Gl[4][4][324];
    const int warp = threadIdx.x >> 6;
    const int lane = threadIdx.x & 63;
    const int wid  = blockIdx.x * 4 + warp;
    if (wid >= NWAVE_) return;
    const int g = lane >> 4, j = lane & 15;
    const int jj = j, kq4 = g * 4;
    const int pl = lane & 31, chb = (lane >> 5) * 8;

    for (int s = 0; s < 4; ++s) {
        const int id = wid*4 + s;
        const int n = id / NBB_, rem = id % NBB_;
        const int bi = rem / NB_, bj = rem % NB_;
        const int pbase = n*(A_*PLANE_) + bi*4*W_ + bj*4;
        float a0=0.f, a1=0.f, a2=0.f, a3=0.f;
        for (int h = 0; h < 2; ++h) {
            const int p = h*32 + pl;
            const int base = pbase + (p>>3)*W_ + (p&7);
            __builtin_amdgcn_wave_barrier();
            #pragma unroll
            for (int a = 0; a < 8; ++a)
                Mt[warp][chb + a][pl] = x[base + (chb + a)*PLANE_];
            __builtin_amdgcn_wave_barrier();
            #pragma unroll
            for (int p4 = 0; p4 < 32; p4 += 4) {
                const float4 av = *(const float4*)&Mt[warp][jj][p4];
                const float4 b0 = *(const float4*)&Mt[warp][kq4+0][p4];
                const float4 b1 = *(const float4*)&Mt[warp][kq4+1][p4];
                const float4 b2 = *(const float4*)&Mt[warp][kq4+2][p4];
                const float4 b3 = *(const float4*)&Mt[warp][kq4+3][p4];
                a0 += av.x*b0.x + av.y*b0.y + av.z*b0.z + av.w*b0.w;
                a1 += av.x*b1.x + av.y*b1.y + av.z*b1.z + av.w*b1.w;
                a2 += av.x*b2.x + av.y*b2.y + av.z*b2.z + av.w*b2.w;
                a3 += av.x*b3.x + av.y*b3.y + av.z*b3.z + av.w*b3.w;
            }
            __builtin_amdgcn_wave_barrier();
        }
        *(float4*)&Gl[warp][s][jj*20 + kq4] = make_float4(a0,a1,a2,a3);
    }
    __builtin_amdgcn_wave_barrier();
    float w[16];
    {
        const float4 t0 = *(const float4*)&Gl[warp][g][j*20 + 0];
        const float4 t1 = *(const float4*)&Gl[warp][g][j*20 + 4];
        const float4 t2 = *(const float4*)&Gl[warp][g][j*20 + 8];
        const float4 t3 = *(const float4*)&Gl[warp][g][j*20 + 12];
        w[0]=t0.x; w[1]=t0.y; w[2]=t0.z; w[3]=t0.w;
        w[4]=t1.x; w[5]=t1.y; w[6]=t1.z; w[7]=t1.w;
        w[8]=t2.x; w[9]=t2.y; w[10]=t2.z; w[11]=t2.w;
        w[12]=t3.x; w[13]=t3.y; w[14]=t3.z; w[15]=t3.w;
    }
    float nrm = 0.f;
    #pragma unroll
    for (int i = 0; i < 16; ++i) nrm += w[i]*w[i];
    for (int sweep = 0; sweep < NSWEEP_; ++sweep) {
        jacobi_round<1>(w, nrm, j);  jacobi_round<2>(w, nrm, j);
        jacobi_round<3>(w, nrm, j);  jacobi_round<4>(w, nrm, j);
        jacobi_round<5>(w, nrm, j);  jacobi_round<6>(w, nrm, j);
        jacobi_round<7>(w, nrm, j);  jacobi_round<8>(w, nrm, j);
        jacobi_round<9>(w, nrm, j);  jacobi_round<10>(w, nrm, j);
        jacobi_round<11>(w, nrm, j); jacobi_round<12>(w, nrm, j);
        jacobi_round<13>(w, nrm, j); jacobi_round<14>(w, nrm, j);
        jacobi_round<15>(w, nrm, j);
    }
    nrm = 0.f;
    #pragma unroll
    for (int i = 0; i < 16; ++i) nrm += w[i]*w[i];
    float rho = 0.f;
    if (nrm > 16.f) {
        const float lam = sqrtf(nrm);
        rho = (1.f - 2.f/sqrtf(lam)) / nrm;
    }
    __builtin_amdgcn_wave_barrier();
    *(float4*)&Gl[warp][g][j*20 + 0]  = make_float4(w[0],w[1],w[2],w[3]);
    *(float4*)&Gl[warp][g][j*20 + 4]  = make_float4(w[4],w[5],w[6],w[7]);
    *(float4*)&Gl[warp][g][j*20 + 8]  = make_float4(w[8],w[9],w[10],w[11]);
    *(float4*)&Gl[warp][g][j*20 + 12] = make_float4(w[12],w[13],w[14],w[15]);
    Gl[warp][g][j*20 + 16] = rho;
    __builtin_amdgcn_wave_barrier();
    float phi[16];
    #pragma unroll
    for (int i = 0; i < 16; ++i) phi[i] = 0.f;
    #pragma unroll
    for (int k = 0; k < 16; ++k) {
        const float coef = Gl[warp][g][k*20 + 16] * Gl[warp][g][k*20 + j];
        const float4 c0 = *(const float4*)&Gl[warp][g][k*20 + 0];
        const float4 c1 = *(const float4*)&Gl[warp][g][k*20 + 4];
        const float4 c2 = *(const float4*)&Gl[warp][g][k*20 + 8];
        const float4 c3 = *(const float4*)&Gl[warp][g][k*20 + 12];
        phi[0]+=coef*c0.x; phi[1]+=coef*c0.y; phi[2]+=coef*c0.z; phi[3]+=coef*c0.w;
        phi[4]+=coef*c1.x; phi[5]+=coef*c1.y; phi[6]+=coef*c1.z; phi[7]+=coef*c1.w;
        phi[8]+=coef*c2.x; phi[9]+=coef*c2.y; phi[10]+=coef*c2.z; phi[11]+=coef*c2.w;
        phi[12]+=coef*c3.x; phi[13]+=coef*c3.y; phi[14]+=coef*c3.z; phi[15]+=coef*c3.w;
    }
    __builtin_amdgcn_wave_barrier();
    *(float4*)&Gl[warp][g][j*20 + 0]  = make_float4(phi[0],phi[1],phi[2],phi[3]);
    *(float4*)&Gl[warp][g][j*20 + 4]  = make_float4(phi[4],phi[5],phi[6],phi[7]);
    *(float4*)&Gl[warp][g][j*20 + 8]  = make_float4(phi[8],phi[9],phi[10],phi[11]);
    *(float4*)&Gl[warp][g][j*20 + 12] = make_float4(phi[12],phi[13],phi[14],phi[15]);
    __builtin_amdgcn_wave_barrier();
    const int pr = lane >> 3, pc = lane & 7;
    for (int s = 0; s < 4; ++s) {
        const int id = wid*4 + s;
        const int n = id / NBB_, rem = id % NBB_;
        const int bi = rem / NB_, bj = rem % NB_;
        const int base = n*(A_*PLANE_) + (bi*4+pr)*W_ + (bj*4+pc);
        float mr[16];
        #pragma unroll
        for (int a = 0; a < 16; ++a) mr[a] = x[base + a*PLANE_];
        float o[16];
        #pragma unroll
        for (int a = 0; a < 16; ++a) o[a] = 0.f;
        #pragma unroll
        for (int k = 0; k < 16; ++k) {
            const float mk = mr[k];
            const float4 f0 = *(const float4*)&Gl[warp][s][k*20 + 0];
            const float4 f1 = *(const float4*)&Gl[warp][s][k*20 + 4];
            const float4 f2 = *(const float4*)&Gl[warp][s][k*20 + 8];
            const float4 f3 = *(const float4*)&Gl[warp][s][k*20 + 12];
            o[0]+=mk*f0.x;  o[1]+=mk*f0.y;  o[2]+=mk*f0.z;  o[3]+=mk*f0.w;
            o[4]+=mk*f1.x;  o[5]+=mk*f1.y;  o[6]+=mk*f1.z;  o[7]+=mk*f1.w;
            o[8]+=mk*f2.x;  o[9]+=mk*f2.y;  o[10]+=mk*f2.z; o[11]+=mk*f2.w;
            o[12]+=mk*f3.x; o[13]+=mk*f3.y; o[14]+=mk*f3.z; o[15]+=mk*f3.w;
        }
        #pragma unroll
        for (int a = 0; a < 16; ++a)
            unsafeAtomicAdd(&out[base + a*PLANE_], o[a]);
    }
}

__global__ __launch_bounds__(256)
void llr_div(float* __restrict__ out, const float* __restrict__ bw) {
    const int i = (blockIdx.x * 256 + threadIdx.x) * 4;
    float4 o = *(float4*)&out[i];
    const float4 b = *(const float4*)&bw[i % PLANE_];
    o.x /= b.x; o.y /= b.y; o.z /= b.z; o.w /= b.w;
    *(float4*)&out[i] = o;
}

extern "C" void kernel_launch(void* const* d_in, const int* in_sizes, int n_in,
                              void* d_out, int out_size, void* d_ws, size_t ws_size,
                              hipStream_t stream) {
    (void)in_sizes; (void)n_in;
    const float* x  = (const float*)d_in[0];
    const float* bw = (const float*)d_in[1];
    float* out = (float*)d_out;

    if (ws_size >= PHI_BYTES_) {
        float* phiG = (float*)d_ws;
        hipLaunchKernelGGL(llr_phi, dim3((NWAVE_ + 3) / 4), dim3(256), 0, stream, x, phiG);
        hipLaunchKernelGGL(llr_out, dim3(N_*NC_*NC_ / 4), dim3(256), 0, stream, x, phiG, out);
    } else {
        hipMemsetAsync(out, 0, (size_t)out_size * sizeof(float), stream);
        hipLaunchKernelGGL(llr_fused, dim3((NWAVE_ + 3) / 4), dim3(256), 0, stream, x, out);
        hipLaunchKernelGGL(llr_div, dim3((N_*A_*PLANE_) / (256*4)), dim3(256), 0, stream, out, bw);
    }
}

// Round 6
// 244.380 us; speedup vs baseline: 1.7363x; 1.0859x over previous
//
#include <hip/hip_runtime.h>

// LocallyLowRank: N=4, A=16, H=W=384, 8x8 blocks stride 4 -> NB=95.
// out[p,:] = x[p,:] * S_p / w_p,  S_p = sum_{b covering p} Phi_b,
// Phi_b = V max(1-2/sigma,0)/1 V^T from G = m_b^T m_b (one-sided Jacobi).
//
// R6: (1) packed fp32 (v_pk_fma_f32) throughout llr_phi's hot loops via
// float2 ext_vector + __builtin_elementwise_fma; (2) llr_out rewritten:
// 8x32-px tile per block, S staged in LDS (weight folded), lane = pixel ->
// 128-256B coalesced global access, x read once, out written once.

typedef __attribute__((ext_vector_type(2))) float v2f;
typedef union { float4 f4; v2f v2[2]; } f4v2;

#define N_      4
#define A_      16
#define H_      384
#define W_      384
#define PLANE_  (H_*W_)       // 147456
#define NB_     95
#define NBB_    (NB_*NB_)     // 9025
#define NMAT_   (N_*NBB_)     // 36100
#define NWAVE_  ((NMAT_ + 3) / 4)   // 9025
#define NSWEEP_ 4
#define PHI_BYTES_ ((size_t)NMAT_ * 256 * 4)   // 36.97 MB

// ---- 16-lane xor exchange: DPP for masks 1,2,3,7,15; ds_swizzle otherwise ---
template<int M>
__device__ __forceinline__ float lane_xor16(float v) {
    if constexpr (M == 1 || M == 2 || M == 3) {
        constexpr int ctrl = (0^M) | ((1^M)<<2) | ((2^M)<<4) | ((3^M)<<6);
        union { float f; int i; } u; u.f = v;
        u.i = __builtin_amdgcn_mov_dpp(u.i, ctrl, 0xF, 0xF, true);
        return u.f;
    } else if constexpr (M == 7) {          // row_half_mirror
        union { float f; int i; } u; u.f = v;
        u.i = __builtin_amdgcn_mov_dpp(u.i, 0x141, 0xF, 0xF, true);
        return u.f;
    } else if constexpr (M == 15) {         // row_mirror
        union { float f; int i; } u; u.f = v;
        u.i = __builtin_amdgcn_mov_dpp(u.i, 0x140, 0xF, 0xF, true);
        return u.f;
    } else {
        return __shfl_xor(v, M, 16);        // ds_swizzle
    }
}

// One Jacobi rotation round on packed column state w[8] (=16 floats).
template<int M>
__device__ __forceinline__ void jacobi_round(v2f w[8], float& nrm, const int j) {
    v2f pw[8];
    #pragma unroll
    for (int i = 0; i < 8; ++i) {
        pw[i][0] = lane_xor16<M>(w[i][0]);
        pw[i][1] = lane_xor16<M>(w[i][1]);
    }
    const float pn = lane_xor16<M>(nrm);

    v2f d0 = w[0]*pw[0], d1 = w[1]*pw[1];
    #pragma unroll
    for (int i = 2; i < 8; i += 2) {
        d0 = __builtin_elementwise_fma(w[i],   pw[i],   d0);
        d1 = __builtin_elementwise_fma(w[i+1], pw[i+1], d1);
    }
    const v2f dsum = d0 + d1;
    const float gam = dsum[0] + dsum[1];

    const bool  low = ((j ^ M) > j);        // canonical order -> identical c,s
    const float na  = low ? nrm : pn;
    const float nb  = low ? pn  : nrm;

    const float thr = 1e-12f * (na + nb);
    const bool  rot = fabsf(gam) > thr;
    const float gs  = rot ? gam : 1.f;
    const float zeta = (nb - na) / (2.f * gs);
    float t = copysignf(1.f, zeta) / (fabsf(zeta) + sqrtf(1.f + zeta*zeta));
    float c = rsqrtf(1.f + t*t);
    float sv = c * t;
    if (!rot) { c = 1.f; sv = 0.f; }

    const float ss = low ? -sv : sv;
    const v2f c2 = {c, c}, sp = {ss, ss};
    #pragma unroll
    for (int i = 0; i < 8; ++i)
        w[i] = __builtin_elementwise_fma(c2, w[i], sp*pw[i]);   // pk_mul+pk_fma

    const float cc = c*c, s2 = sv*sv, x2 = 2.f*c*sv*gam;
    nrm = low ? (cc*na + s2*nb - x2) : (s2*na + cc*nb + x2);
}

// Shared phases 1-4: Gram + Jacobi + Phi (writes Phi into Gl; caller disposes).
// One wave, 4 matrices, 16 lanes/matrix. No block barriers.
__device__ __forceinline__ void gram_jacobi_phi(
        const float* __restrict__ x, const int wid, const int warp,
        const int lane, float Mt[4][16][20], float Gl[4][4][324]) {
    const int g   = lane >> 4;
    const int j   = lane & 15;
    const int kq4 = g * 4;

    // -------- Phase 1: stage + Gram (4 matrices x 4 quarter-staged) ---------
    for (int s = 0; s < 4; ++s) {
        const int id  = wid * 4 + s;
        const int n   = id / NBB_;
        const int rem = id % NBB_;
        const int bi  = rem / NB_;
        const int bj  = rem % NB_;
        const int pbase = n * (A_ * PLANE_) + bi*4*W_ + bj*4;

        v2f acc0 = {0,0}, acc1 = {0,0}, acc2 = {0,0}, acc3 = {0,0};
        for (int q = 0; q < 4; ++q) {
            const int p    = q*16 + j;
            const int base = pbase + (p >> 3) * W_ + (p & 7);
            __builtin_amdgcn_wave_barrier();
            #pragma unroll
            for (int t = 0; t < 4; ++t)
                Mt[warp][kq4 + t][j] = x[base + (kq4 + t) * PLANE_];
            __builtin_amdgcn_wave_barrier();

            #pragma unroll
            for (int p4 = 0; p4 < 16; p4 += 4) {
                f4v2 av, b0, b1, b2, b3;
                av.f4 = *(const float4*)&Mt[warp][j][p4];
                b0.f4 = *(const float4*)&Mt[warp][kq4 + 0][p4];
                b1.f4 = *(const float4*)&Mt[warp][kq4 + 1][p4];
                b2.f4 = *(const float4*)&Mt[warp][kq4 + 2][p4];
                b3.f4 = *(const float4*)&Mt[warp][kq4 + 3][p4];
                #pragma unroll
                for (int h = 0; h < 2; ++h) {
                    acc0 = __builtin_elementwise_fma(av.v2[h], b0.v2[h], acc0);
                    acc1 = __builtin_elementwise_fma(av.v2[h], b1.v2[h], acc1);
                    acc2 = __builtin_elementwise_fma(av.v2[h], b2.v2[h], acc2);
                    acc3 = __builtin_elementwise_fma(av.v2[h], b3.v2[h], acc3);
                }
            }
            __builtin_amdgcn_wave_barrier();
        }
        *(float4*)&Gl[warp][s][j*20 + kq4] =
            make_float4(acc0[0]+acc0[1], acc1[0]+acc1[1],
                        acc2[0]+acc2[1], acc3[0]+acc3[1]);
    }
    __builtin_amdgcn_wave_barrier();

    // -------- Phase 2: my column into registers -----------------------------
    v2f w[8];
    {
        f4v2 t0, t1, t2, t3;
        t0.f4 = *(const float4*)&Gl[warp][g][j*20 + 0];
        t1.f4 = *(const float4*)&Gl[warp][g][j*20 + 4];
        t2.f4 = *(const float4*)&Gl[warp][g][j*20 + 8];
        t3.f4 = *(const float4*)&Gl[warp][g][j*20 + 12];
        w[0]=t0.v2[0]; w[1]=t0.v2[1]; w[2]=t1.v2[0]; w[3]=t1.v2[1];
        w[4]=t2.v2[0]; w[5]=t2.v2[1]; w[6]=t3.v2[0]; w[7]=t3.v2[1];
    }
    float nrm;
    {
        v2f d = w[0]*w[0];
        #pragma unroll
        for (int i = 1; i < 8; ++i) d = __builtin_elementwise_fma(w[i], w[i], d);
        nrm = d[0] + d[1];
    }

    // -------- Phase 3: one-sided Jacobi -------------------------------------
    for (int sweep = 0; sweep < NSWEEP_; ++sweep) {
        jacobi_round<1>(w, nrm, j);  jacobi_round<2>(w, nrm, j);
        jacobi_round<3>(w, nrm, j);  jacobi_round<4>(w, nrm, j);
        jacobi_round<5>(w, nrm, j);  jacobi_round<6>(w, nrm, j);
        jacobi_round<7>(w, nrm, j);  jacobi_round<8>(w, nrm, j);
        jacobi_round<9>(w, nrm, j);  jacobi_round<10>(w, nrm, j);
        jacobi_round<11>(w, nrm, j); jacobi_round<12>(w, nrm, j);
        jacobi_round<13>(w, nrm, j); jacobi_round<14>(w, nrm, j);
        jacobi_round<15>(w, nrm, j);
    }
    {   // exact norm (drift removal)
        v2f d = w[0]*w[0];
        #pragma unroll
        for (int i = 1; i < 8; ++i) d = __builtin_elementwise_fma(w[i], w[i], d);
        nrm = d[0] + d[1];
    }
    float rho = 0.f;                         // max(1-2/sigma,0)/lam^2
    if (nrm > 16.f) {
        const float lam = sqrtf(nrm);
        rho = (1.f - 2.f / sqrtf(lam)) / nrm;
    }

    __builtin_amdgcn_wave_barrier();
    *(float4*)&Gl[warp][g][j*20 + 0]  = make_float4(w[0][0], w[0][1], w[1][0], w[1][1]);
    *(float4*)&Gl[warp][g][j*20 + 4]  = make_float4(w[2][0], w[2][1], w[3][0], w[3][1]);
    *(float4*)&Gl[warp][g][j*20 + 8]  = make_float4(w[4][0], w[4][1], w[5][0], w[5][1]);
    *(float4*)&Gl[warp][g][j*20 + 12] = make_float4(w[6][0], w[6][1], w[7][0], w[7][1]);
    Gl[warp][g][j*20 + 16] = rho;
    __builtin_amdgcn_wave_barrier();

    // -------- Phase 4: Phi col j = sum_k rho_k w_k[j] w_k (into registers) --
    v2f ph[8];
    #pragma unroll
    for (int i = 0; i < 8; ++i) ph[i] = (v2f){0.f, 0.f};
    #pragma unroll
    for (int k = 0; k < 16; ++k) {
        const float coef = Gl[warp][g][k*20 + 16] * Gl[warp][g][k*20 + j];
        const v2f cf = {coef, coef};
        f4v2 c0, c1, c2r, c3;
        c0.f4  = *(const float4*)&Gl[warp][g][k*20 + 0];
        c1.f4  = *(const float4*)&Gl[warp][g][k*20 + 4];
        c2r.f4 = *(const float4*)&Gl[warp][g][k*20 + 8];
        c3.f4  = *(const float4*)&Gl[warp][g][k*20 + 12];
        ph[0] = __builtin_elementwise_fma(cf, c0.v2[0],  ph[0]);
        ph[1] = __builtin_elementwise_fma(cf, c0.v2[1],  ph[1]);
        ph[2] = __builtin_elementwise_fma(cf, c1.v2[0],  ph[2]);
        ph[3] = __builtin_elementwise_fma(cf, c1.v2[1],  ph[3]);
        ph[4] = __builtin_elementwise_fma(cf, c2r.v2[0], ph[4]);
        ph[5] = __builtin_elementwise_fma(cf, c2r.v2[1], ph[5]);
        ph[6] = __builtin_elementwise_fma(cf, c3.v2[0],  ph[6]);
        ph[7] = __builtin_elementwise_fma(cf, c3.v2[1],  ph[7]);
    }
    __builtin_amdgcn_wave_barrier();          // all W reads done -> overwrite
    *(float4*)&Gl[warp][g][j*20 + 0]  = make_float4(ph[0][0], ph[0][1], ph[1][0], ph[1][1]);
    *(float4*)&Gl[warp][g][j*20 + 4]  = make_float4(ph[2][0], ph[2][1], ph[3][0], ph[3][1]);
    *(float4*)&Gl[warp][g][j*20 + 8]  = make_float4(ph[4][0], ph[4][1], ph[5][0], ph[5][1]);
    *(float4*)&Gl[warp][g][j*20 + 12] = make_float4(ph[6][0], ph[6][1], ph[7][0], ph[7][1]);
    __builtin_amdgcn_wave_barrier();
}

// =================== K1: Phi per block -> global ============================
__global__ __launch_bounds__(256, 6)
void llr_phi(const float* __restrict__ x, float* __restrict__ phiG) {
    __shared__ __align__(16) float Mt[4][16][20];
    __shared__ __align__(16) float Gl[4][4][324];
    const int warp = threadIdx.x >> 6;
    const int lane = threadIdx.x & 63;
    const int wid  = blockIdx.x * 4 + warp;
    if (wid >= NWAVE_) return;

    gram_jacobi_phi(x, wid, warp, lane, Mt, Gl);

    // Phi symmetric -> column j IS row j: 64B contiguous store per lane.
    const int g = lane >> 4, j = lane & 15;
    float* pb = phiG + (size_t)(wid*4 + g) * 256 + j * 16;
    const float4 p0 = *(const float4*)&Gl[warp][g][j*20 + 0];
    const float4 p1 = *(const float4*)&Gl[warp][g][j*20 + 4];
    const float4 p2 = *(const float4*)&Gl[warp][g][j*20 + 8];
    const float4 p3 = *(const float4*)&Gl[warp][g][j*20 + 12];
    *(float4*)&pb[0]  = p0;  *(float4*)&pb[4]  = p1;
    *(float4*)&pb[8]  = p2;  *(float4*)&pb[12] = p3;
}

// =================== K2: out = x * (sum Phi)/w, tiled 8x32 px ===============
// Block: 8 rows x 32 cols = 2x8 = 16 cells. Stage S (weight-folded) in LDS,
// then lane = pixel -> coalesced global loads/stores, x read once.
__global__ __launch_bounds__(256, 6)
void llr_out2(const float* __restrict__ x, const float* __restrict__ phiG,
              float* __restrict__ out) {
    __shared__ __align__(16) float Sl[16][260];   // stride 260: conflict-free reads

    const int b  = blockIdx.x;          // 4 * 48 * 12 = 2304
    const int n  = b / 576;
    const int tt = b % 576;
    const int tr = tt / 12, tc = tt % 12;
    const int r0 = tr*8, c0 = tc*32;
    const int cr0 = tr*2, cc0 = tc*8;   // global cell coords of tile origin

    // -------- stage S: 16 threads per cell, float4 each, 4 iterations -------
    {
        const int lc = threadIdx.x >> 4;         // local cell 0..15
        const int fo = (threadIdx.x & 15) * 4;   // float offset 0..60
        const int ci = cr0 + (lc >> 3);
        const int cj = cc0 + (lc & 7);
        const float invw = 1.f / (float)(((ci >= 1) + (ci <= NB_-1)) *
                                         ((cj >= 1) + (cj <= NB_-1)));
        #pragma unroll
        for (int it = 0; it < 4; ++it) {
            const int off = fo + it*64;
            float4 s = make_float4(0.f, 0.f, 0.f, 0.f);
            #pragma unroll
            for (int dbi = -1; dbi <= 0; ++dbi) {
                const int bi = ci + dbi;
                if (bi < 0 || bi > NB_-1) continue;
                #pragma unroll
                for (int dbj = -1; dbj <= 0; ++dbj) {
                    const int bj = cj + dbj;
                    if (bj < 0 || bj > NB_-1) continue;
                    const float4 p = *(const float4*)
                        &phiG[((size_t)(n*NBB_ + bi*NB_ + bj))*256 + off];
                    s.x += p.x; s.y += p.y; s.z += p.z; s.w += p.w;
                }
            }
            s.x *= invw; s.y *= invw; s.z *= invw; s.w *= invw;
            *(float4*)&Sl[lc][off] = s;
        }
    }
    __syncthreads();

    // -------- compute: thread = 1 pixel, all 16 channels --------------------
    const int r = threadIdx.x >> 5;          // 0..7 (wave = 2 rows, same cell-row)
    const int c = threadIdx.x & 31;          // 0..31 -> coalesced
    const int lcc = ((r >> 2) << 3) + (c >> 2);
    const size_t sb = (size_t)n * (A_*PLANE_) + (size_t)(r0 + r) * W_ + (c0 + c);

    float xk[16];
    #pragma unroll
    for (int k = 0; k < 16; ++k) xk[k] = x[sb + (size_t)k * PLANE_];

    v2f acc[8];
    #pragma unroll
    for (int i = 0; i < 8; ++i) acc[i] = (v2f){0.f, 0.f};
    #pragma unroll
    for (int k = 0; k < 16; ++k) {
        const v2f xv = {xk[k], xk[k]};
        f4v2 s0, s1, s2, s3;
        s0.f4 = *(const float4*)&Sl[lcc][k*16 + 0];   // 8 cells x disjoint banks,
        s1.f4 = *(const float4*)&Sl[lcc][k*16 + 4];   // 8-lane broadcast: cf-free
        s2.f4 = *(const float4*)&Sl[lcc][k*16 + 8];
        s3.f4 = *(const float4*)&Sl[lcc][k*16 + 12];
        acc[0] = __builtin_elementwise_fma(xv, s0.v2[0], acc[0]);
        acc[1] = __builtin_elementwise_fma(xv, s0.v2[1], acc[1]);
        acc[2] = __builtin_elementwise_fma(xv, s1.v2[0], acc[2]);
        acc[3] = __builtin_elementwise_fma(xv, s1.v2[1], acc[3]);
        acc[4] = __builtin_elementwise_fma(xv, s2.v2[0], acc[4]);
        acc[5] = __builtin_elementwise_fma(xv, s2.v2[1], acc[5]);
        acc[6] = __builtin_elementwise_fma(xv, s3.v2[0], acc[6]);
        acc[7] = __builtin_elementwise_fma(xv, s3.v2[1], acc[7]);
    }
    #pragma unroll
    for (int i = 0; i < 8; ++i) {
        out[sb + (size_t)(2*i)     * PLANE_] = acc[i][0];
        out[sb + (size_t)(2*i + 1) * PLANE_] = acc[i][1];
    }
}

// =================== Fallback (ws too small): fused + atomics ===============
__global__ __launch_bounds__(256, 5)
void llr_fused(const float* __restrict__ x, float* __restrict__ out) {
    __shared__ __align__(16) float Mt[4][16][20];
    __shared__ __align__(16) float Gl[4][4][324];
    const int warp = threadIdx.x >> 6;
    const int lane = threadIdx.x & 63;
    const int wid  = blockIdx.x * 4 + warp;
    if (wid >= NWAVE_) return;

    gram_jacobi_phi(x, wid, warp, lane, Mt, Gl);

    const int pr = lane >> 3, pc = lane & 7;
    for (int s = 0; s < 4; ++s) {
        const int id = wid*4 + s;
        const int n = id / NBB_, rem = id % NBB_;
        const int bi = rem / NB_, bj = rem % NB_;
        const int base = n*(A_*PLANE_) + (bi*4+pr)*W_ + (bj*4+pc);
        float mr[16];
        #pragma unroll
        for (int a = 0; a < 16; ++a) mr[a] = x[base + a*PLANE_];
        float o[16];
        #pragma unroll
        for (int a = 0; a < 16; ++a) o[a] = 0.f;
        #pragma unroll
        for (int k = 0; k < 16; ++k) {
            const float mk = mr[k];
            const float4 f0 = *(const float4*)&Gl[warp][s][k*20 + 0];
            const float4 f1 = *(const float4*)&Gl[warp][s][k*20 + 4];
            const float4 f2 = *(const float4*)&Gl[warp][s][k*20 + 8];
            const float4 f3 = *(const float4*)&Gl[warp][s][k*20 + 12];
            o[0]+=mk*f0.x;  o[1]+=mk*f0.y;  o[2]+=mk*f0.z;  o[3]+=mk*f0.w;
            o[4]+=mk*f1.x;  o[5]+=mk*f1.y;  o[6]+=mk*f1.z;  o[7]+=mk*f1.w;
            o[8]+=mk*f2.x;  o[9]+=mk*f2.y;  o[10]+=mk*f2.z; o[11]+=mk*f2.w;
            o[12]+=mk*f3.x; o[13]+=mk*f3.y; o[14]+=mk*f3.z; o[15]+=mk*f3.w;
        }
        #pragma unroll
        for (int a = 0; a < 16; ++a)
            unsafeAtomicAdd(&out[base + a*PLANE_], o[a]);
    }
}

__global__ __launch_bounds__(256)
void llr_div(float* __restrict__ out, const float* __restrict__ bw) {
    const int i = (blockIdx.x * 256 + threadIdx.x) * 4;
    float4 o = *(float4*)&out[i];
    const float4 bv = *(const float4*)&bw[i % PLANE_];
    o.x /= bv.x; o.y /= bv.y; o.z /= bv.z; o.w /= bv.w;
    *(float4*)&out[i] = o;
}

extern "C" void kernel_launch(void* const* d_in, const int* in_sizes, int n_in,
                              void* d_out, int out_size, void* d_ws, size_t ws_size,
                              hipStream_t stream) {
    (void)in_sizes; (void)n_in;
    const float* x  = (const float*)d_in[0];
    const float* bw = (const float*)d_in[1];
    float* out = (float*)d_out;

    if (ws_size >= PHI_BYTES_) {
        float* phiG = (float*)d_ws;
        hipLaunchKernelGGL(llr_phi,  dim3((NWAVE_ + 3) / 4), dim3(256), 0, stream, x, phiG);
        hipLaunchKernelGGL(llr_out2, dim3(4 * 48 * 12),      dim3(256), 0, stream, x, phiG, out);
    } else {
        hipMemsetAsync(out, 0, (size_t)out_size * sizeof(float), stream);
        hipLaunchKernelGGL(llr_fused, dim3((NWAVE_ + 3) / 4), dim3(256), 0, stream, x, out);
        hipLaunchKernelGGL(llr_div, dim3((N_*A_*PLANE_) / (256*4)), dim3(256), 0, stream, out, bw);
    }
}